// Round 7
// baseline (402.681 us; speedup 1.0000x reference)
//
#include <hip/hip_runtime.h>
#include <hip/hip_fp16.h>
#include <math.h>

// Problem constants (from setup_inputs): B=2, C=256, N=4096
#define NB 2
#define NC 256
#define NN 4096
#define MAX_ITER 10

#define PBLOCKS 512                    // fused-pass blocks (256 per batch)
#define PCHUNKS 256                    // partial chunks per batch
#define PROWS 16                       // rows per fused-pass block (2 per wave)

#define LDA 72                         // padded LDS row stride (halfs)
#define C8S 144                        // padded C8 byte stride

typedef _Float16 half8_t __attribute__((ext_vector_type(8)));
typedef float f32x4 __attribute__((ext_vector_type(4)));
typedef float f32x2 __attribute__((ext_vector_type(2)));

// Decode 16 fp8 (e4m3, packed in uint4) -> 16 floats. HW cvt, gfx950.
__device__ inline void fp8x16_decode(uint4 v, float* o) {
  f32x2 p;
  p = __builtin_amdgcn_cvt_pk_f32_fp8(v.x, false); o[0] = p[0];  o[1] = p[1];
  p = __builtin_amdgcn_cvt_pk_f32_fp8(v.x, true);  o[2] = p[0];  o[3] = p[1];
  p = __builtin_amdgcn_cvt_pk_f32_fp8(v.y, false); o[4] = p[0];  o[5] = p[1];
  p = __builtin_amdgcn_cvt_pk_f32_fp8(v.y, true);  o[6] = p[0];  o[7] = p[1];
  p = __builtin_amdgcn_cvt_pk_f32_fp8(v.z, false); o[8] = p[0];  o[9] = p[1];
  p = __builtin_amdgcn_cvt_pk_f32_fp8(v.z, true);  o[10] = p[0]; o[11] = p[1];
  p = __builtin_amdgcn_cvt_pk_f32_fp8(v.w, false); o[12] = p[0]; o[13] = p[1];
  p = __builtin_amdgcn_cvt_pk_f32_fp8(v.w, true);  o[14] = p[0]; o[15] = p[1];
}

// Decode 8 fp8 (e4m3, packed in uint2) -> 8 floats.
__device__ inline void fp8x8_decode(uint2 v, float* o) {
  f32x2 p;
  p = __builtin_amdgcn_cvt_pk_f32_fp8(v.x, false); o[0] = p[0]; o[1] = p[1];
  p = __builtin_amdgcn_cvt_pk_f32_fp8(v.x, true);  o[2] = p[0]; o[3] = p[1];
  p = __builtin_amdgcn_cvt_pk_f32_fp8(v.y, false); o[4] = p[0]; o[5] = p[1];
  p = __builtin_amdgcn_cvt_pk_f32_fp8(v.y, true);  o[6] = p[0]; o[7] = p[1];
}

// ---------------------------------------------------------------------------
// 1) inv_norm[b,n] = 1/sqrt(sum_c feats[b,c,n]^2 + 1e-6)
__global__ __launch_bounds__(256) void norms_kernel(
    const float* __restrict__ f1, const float* __restrict__ f2,
    float* __restrict__ inv1, float* __restrict__ inv2) {
  int n = blockIdx.x * 256 + threadIdx.x;
  int b = blockIdx.y;
  const float* f = blockIdx.z ? f2 : f1;
  float* o = blockIdx.z ? inv2 : inv1;
  const float* base = f + (size_t)b * NC * NN + n;
  float s = 0.f;
#pragma unroll 8
  for (int c = 0; c < NC; ++c) {
    float v = base[(size_t)c * NN];
    s = fmaf(v, v, s);
  }
  o[b * NN + n] = 1.0f / sqrtf(s + 1e-6f);
}

// ---------------------------------------------------------------------------
// 1b) prep: f_t[b][n][c] = f[b][c][n] * inv[b][n], cast to f16.
__global__ __launch_bounds__(256) void prep_kernel(
    const float* __restrict__ f1, const float* __restrict__ f2,
    const float* __restrict__ inv1, const float* __restrict__ inv2,
    __half* __restrict__ f1t, __half* __restrict__ f2t) {
  int which = blockIdx.z & 1;
  int b = blockIdx.z >> 1;
  const float* f = which ? f2 : f1;
  const float* inv = which ? inv2 : inv1;
  __half* ft = which ? f2t : f1t;
  int n0 = blockIdx.x * 64;
  int c0 = blockIdx.y * 64;

  __shared__ float T[64][65];
  int t = threadIdx.x;
  int lane = t & 63, grp = t >> 6;
#pragma unroll
  for (int p = 0; p < 16; ++p) {
    int c_in = p * 4 + grp;
    T[lane][c_in] = f[((size_t)b * NC + c0 + c_in) * NN + n0 + lane];
  }
  __syncthreads();
#pragma unroll
  for (int p = 0; p < 16; ++p) {
    int n_out = p * 4 + grp;
    float v = T[n_out][lane] * inv[b * NN + n0 + n_out];
    ft[((size_t)b * NN + n0 + n_out) * NC + c0 + lane] = __float2half(v);
  }
}

// ---------------------------------------------------------------------------
// 2) K[b,i,j] = exp((corr-1)/eps') * (dist < 0.25) via f16 MFMA, fp8 store.
// R7: register double-buffered staging. Tile t+1 is prefetched into regs
// right after the LDS-ready barrier, so its global latency hides under the
// MFMA + next-iteration work instead of serializing load->barrier->MFMA.
// Occupancy is LDS-limited (2 blocks/CU @ 40 KB), so +64 staging VGPRs are
// free (VGPR 76 -> ~140, still far under the 2-waves/SIMD budget).
struct __align__(16) SMstage { __half A[128 * LDA]; __half B[128 * LDA]; };
union SMu { SMstage st; unsigned char C8[128 * C8S]; };

__global__ __launch_bounds__(256) void kmat_mfma_kernel(
    const __half* __restrict__ f1t, const __half* __restrict__ f2t,
    const float* __restrict__ pc1, const float* __restrict__ pc2,
    const float* __restrict__ g_eps, unsigned char* __restrict__ K) {
  int b = blockIdx.z;
  int i0 = blockIdx.y * 128;
  int j0 = blockIdx.x * 128;

  __shared__ SMu sm;
  __shared__ float p1s[4][128];
  __shared__ float p2s[4][128];

  int tid = threadIdx.x;
  if (tid < 128) {
    int i = i0 + tid;
    float x = pc1[((size_t)b * 3 + 0) * NN + i];
    float y = pc1[((size_t)b * 3 + 1) * NN + i];
    float z = pc1[((size_t)b * 3 + 2) * NN + i];
    p1s[0][tid] = x; p1s[1][tid] = y; p1s[2][tid] = z;
    p1s[3][tid] = x * x + y * y + z * z;
  } else {
    int j = j0 + tid - 128;
    float x = pc2[((size_t)b * 3 + 0) * NN + j];
    float y = pc2[((size_t)b * 3 + 1) * NN + j];
    float z = pc2[((size_t)b * 3 + 2) * NN + j];
    p2s[0][tid - 128] = x; p2s[1][tid - 128] = y; p2s[2][tid - 128] = z;
    p2s[3][tid - 128] = x * x + y * y + z * z;
  }
  float inv_eps = 1.0f / (expf(g_eps[0]) + 0.03f);

  const __half* Ag = f1t + ((size_t)b * NN + i0) * NC;
  const __half* Bg = f2t + ((size_t)b * NN + j0) * NC;

  int lane = tid & 63, wid = tid >> 6;
  int m0 = (wid >> 1) * 64, n0 = (wid & 1) * 64;
  int l15 = lane & 15, quad = lane >> 4;

  f32x4 acc[4][4] = {};

  int sr = tid >> 1, sh = tid & 1;
  const __half* Arow = Ag + (size_t)sr * NC + sh * 32;
  const __half* Brow = Bg + (size_t)sr * NC + sh * 32;

  // Preload tile 0 into registers.
  uint4 rA[4], rB[4];
#pragma unroll
  for (int s = 0; s < 4; ++s) {
    rA[s] = ((const uint4*)Arow)[s];
    rB[s] = ((const uint4*)Brow)[s];
  }

  for (int t = 0; t < 4; ++t) {
    __syncthreads();  // LDS free (previous MFMAs done)
    {
      uint4* Ad = (uint4*)&sm.st.A[sr * LDA + sh * 32];
      uint4* Bd = (uint4*)&sm.st.B[sr * LDA + sh * 32];
#pragma unroll
      for (int s = 0; s < 4; ++s) Ad[s] = rA[s];
#pragma unroll
      for (int s = 0; s < 4; ++s) Bd[s] = rB[s];
    }
    __syncthreads();  // LDS ready
    // Prefetch tile t+1; latency hides under the MFMAs below.
    if (t < 3) {
#pragma unroll
      for (int s = 0; s < 4; ++s) {
        rA[s] = ((const uint4*)(Arow + (t + 1) * 64))[s];
        rB[s] = ((const uint4*)(Brow + (t + 1) * 64))[s];
      }
    }
#pragma unroll
    for (int ks = 0; ks < 2; ++ks) {
      half8_t aF[4], bF[4];
#pragma unroll
      for (int mt = 0; mt < 4; ++mt)
        aF[mt] = *(const half8_t*)&sm.st.A[(m0 + mt * 16 + l15) * LDA + ks * 32 + quad * 8];
#pragma unroll
      for (int nt = 0; nt < 4; ++nt)
        bF[nt] = *(const half8_t*)&sm.st.B[(n0 + nt * 16 + l15) * LDA + ks * 32 + quad * 8];
#pragma unroll
      for (int mt = 0; mt < 4; ++mt)
#pragma unroll
        for (int nt = 0; nt < 4; ++nt)
          acc[mt][nt] = __builtin_amdgcn_mfma_f32_16x16x32_f16(
              aF[mt], bF[nt], acc[mt][nt], 0, 0, 0);
    }
  }

  __syncthreads();

  float c2x[4], c2y[4], c2z[4], c2n[4];
#pragma unroll
  for (int nt = 0; nt < 4; ++nt) {
    int c = n0 + nt * 16 + l15;
    c2x[nt] = p2s[0][c]; c2y[nt] = p2s[1][c];
    c2z[nt] = p2s[2][c]; c2n[nt] = p2s[3][c];
  }
#pragma unroll
  for (int mt = 0; mt < 4; ++mt) {
#pragma unroll
    for (int rr = 0; rr < 4; ++rr) {
      int row = m0 + mt * 16 + quad * 4 + rr;
      float px = p1s[0][row], py = p1s[1][row], pz = p1s[2][row];
      float n1 = p1s[3][row];
#pragma unroll
      for (int nt = 0; nt < 4; ++nt) {
        float corr = acc[mt][nt][rr];
        float dist = n1 + c2n[nt] - 2.0f * (px * c2x[nt] + py * c2y[nt] + pz * c2z[nt]);
        float kv = (dist < 0.25f) ? __expf((corr - 1.0f) * inv_eps) : 0.0f;
        unsigned int pk = (unsigned int)__builtin_amdgcn_cvt_pk_fp8_f32(kv, kv, 0, false);
        sm.C8[row * C8S + n0 + nt * 16 + l15] = (unsigned char)(pk & 0xFF);
      }
    }
  }
  __syncthreads();

  // Coalesced fp8 store: 8 threads cover a 128B row, 32 rows per sweep.
  int c8 = tid & 7, rg = tid >> 3;
#pragma unroll
  for (int s = 0; s < 4; ++s) {
    int row = s * 32 + rg;
    uint4 v = *(uint4*)&sm.C8[row * C8S + c8 * 16];
    *(uint4*)&K[((size_t)b * NN + i0 + row) * NN + j0 + c8 * 16] = v;
  }
}

// ---------------------------------------------------------------------------
// 3) Fused Sinkhorn pass over fp8 K. R7: same two-phase structure as R6
// (proven, 350 µs) but 8 waves/block (512 threads), doubling TLP from
// 2 -> 4 waves/SIMD (512 blocks x 8 waves = 4096 waves on 1024 SIMDs).
//   Phase 1 (row-split): wave w owns 2 rows; b loaded per-q (16 floats live
//     at a time -> peak VGPR ~100, not breg64-driven). FMA accumulation
//     order per chain is bit-identical to R0 (q-major, s-minor).
//   Phase 2 (column-split): wave w owns cols [w*512,(w+1)*512) of all 16
//     rows, uint2 loads, ps[8]; part/breduce layouts unchanged.
// No launch_bounds cap (R4/R5 lesson).
__global__ __launch_bounds__(512) void fused_pass_kernel(
    const unsigned char* __restrict__ K, const float* __restrict__ bvec,
    float* __restrict__ part, const float* __restrict__ g_gamma,
    const float* __restrict__ g_eps, int pass) {
  __shared__ float wgt_s[PROWS];  // 64 B

  int g = blockIdx.x;            // 0..511
  int batch = g >> 8;
  int row0 = (g & 255) * PROWS;
  int tid = threadIdx.x;
  int w = tid >> 6, l = tid & 63;  // w: 0..7
  const unsigned char* Kb = K + (size_t)batch * NN * NN;

  float eps = expf(g_eps[0]) + 0.03f;
  float gam = expf(g_gamma[0]) + 0.03f;
  float power = gam / (gam + eps);
  const float probN = 1.0f / NN;

  if (pass > 0) {
    int rbase = row0 + w * 2;  // 2 rows per wave

    // Load the wave's 2 rows (full width): 8 independent 16B loads.
    uint4 kraw[2][4];
#pragma unroll
    for (int r = 0; r < 2; ++r) {
      const uint4* Kr = (const uint4*)(Kb + (size_t)(rbase + r) * NN);
#pragma unroll
      for (int q = 0; q < 4; ++q) kraw[r][q] = Kr[q * 64 + l];
    }

    // Dots: q outer (16-float b slice live), r inner. Chain order (q-major,
    // s-minor) identical to R0's proven body.
    float d0[2] = {}, d1[2] = {}, d2[2] = {}, d3[2] = {};
#pragma unroll
    for (int q = 0; q < 4; ++q) {
      float bq[16];
      const float4* bp = (const float4*)&bvec[batch * NN + (q * 64 + l) * 16];
#pragma unroll
      for (int s = 0; s < 4; ++s) {
        float4 bb = bp[s];
        bq[s * 4 + 0] = bb.x; bq[s * 4 + 1] = bb.y;
        bq[s * 4 + 2] = bb.z; bq[s * 4 + 3] = bb.w;
      }
#pragma unroll
      for (int r = 0; r < 2; ++r) {
        float kf[16];
        fp8x16_decode(kraw[r][q], kf);
#pragma unroll
        for (int s = 0; s < 4; ++s) {
          d0[r] = fmaf(kf[s * 4 + 0], bq[s * 4 + 0], d0[r]);
          d1[r] = fmaf(kf[s * 4 + 1], bq[s * 4 + 1], d1[r]);
          d2[r] = fmaf(kf[s * 4 + 2], bq[s * 4 + 2], d2[r]);
          d3[r] = fmaf(kf[s * 4 + 3], bq[s * 4 + 3], d3[r]);
        }
      }
    }
    // Serial per-row tree + powf (R0's proven pattern).
#pragma unroll
    for (int r = 0; r < 2; ++r) {
      float kbs = (d0[r] + d1[r]) + (d2[r] + d3[r]);
#pragma unroll
      for (int off = 1; off < 64; off <<= 1) kbs += __shfl_xor(kbs, off, 64);
      if (l == 0) wgt_s[w * 2 + r] = __powf(probN / (kbs + 1e-8f), power);
    }
  }

  // Keep phase-2 loads out of phase-1's register peak.
  __builtin_amdgcn_sched_barrier(0);

  // Phase 2 loads: wave w reads ALL 16 rows over its 512-col slice
  // (L2-hot for pass>0). 16 independent 8B loads.
  uint2 k2[PROWS];
#pragma unroll
  for (int r = 0; r < PROWS; ++r)
    k2[r] = *(const uint2*)(Kb + (size_t)(row0 + r) * NN + w * 512 + l * 8);

  if (pass > 0) __syncthreads();  // wgt_s ready (load latency hides here)

  float ps[8];
#pragma unroll
  for (int e = 0; e < 8; ++e) ps[e] = 0.f;
#pragma unroll
  for (int r = 0; r < PROWS; ++r) {
    float wr = (pass == 0) ? probN : wgt_s[r];
    float kf[8];
    fp8x8_decode(k2[r], kf);
#pragma unroll
    for (int e = 0; e < 8; ++e) ps[e] = fmaf(kf[e], wr, ps[e]);
  }

  // Store: wave w's 512-col slice of part[g][:] (2 x 16B per lane).
  float* pout = &part[(size_t)g * NN + w * 512 + l * 8];
  *(float4*)&pout[0] = make_float4(ps[0], ps[1], ps[2], ps[3]);
  *(float4*)&pout[4] = make_float4(ps[4], ps[5], ps[6], ps[7]);
}

// ---------------------------------------------------------------------------
// 3b) b[j] = (probN / (sum_k part[b,k,j] + 1e-8))^power
// 64 cols x 4 k-slices per block; grid (NN/64, NB) = 128 blocks.
__global__ __launch_bounds__(256) void breduce_kernel(
    const float* __restrict__ part, float* __restrict__ bvec,
    const float* __restrict__ g_gamma, const float* __restrict__ g_eps) {
  int b = blockIdx.y;
  int c0 = blockIdx.x * 64;
  int t = threadIdx.x;
  int cl = t & 63, kg = t >> 6;
  const float* p = part + (size_t)(b * PCHUNKS + kg * 64) * NN + c0 + cl;
  float s = 0.f;
#pragma unroll 8
  for (int k = 0; k < 64; ++k) s += p[(size_t)k * NN];
  __shared__ float red[4][64];
  red[kg][cl] = s;
  __syncthreads();
  if (t < 64) {
    float tot = (red[0][t] + red[1][t]) + (red[2][t] + red[3][t]);
    float eps = expf(g_eps[0]) + 0.03f;
    float gam = expf(g_gamma[0]) + 0.03f;
    float power = gam / (gam + eps);
    bvec[b * NN + c0 + t] = __powf((1.0f / NN) / (tot + 1e-8f), power);
  }
}

// ---------------------------------------------------------------------------
// 4) Final pass fused: Kb + Sxyz, then a_10 and flow. fp8 K.
__global__ __launch_bounds__(256) void kb_flow_kernel(
    const unsigned char* __restrict__ K, const float* __restrict__ bvec,
    const float* __restrict__ pc1, const float* __restrict__ pc2,
    const float* __restrict__ g_gamma, const float* __restrict__ g_eps,
    float* __restrict__ out) {
  int b = blockIdx.y;
  int i = blockIdx.x;
  int j16 = threadIdx.x;  // 0..255
  const uint4* K16 = (const uint4*)(K + ((size_t)b * NN + i) * NN);
  uint4 kv = K16[j16];
  float kf[16];
  fp8x16_decode(kv, kf);

  const float4* b4 = (const float4*)&bvec[b * NN + j16 * 16];
  const float* p2 = pc2 + (size_t)b * 3 * NN;
  const float4* p2x = (const float4*)&p2[0 * NN + j16 * 16];
  const float4* p2y = (const float4*)&p2[1 * NN + j16 * 16];
  const float4* p2z = (const float4*)&p2[2 * NN + j16 * 16];

  float S = 0.f, Sx = 0.f, Sy = 0.f, Sz = 0.f;
#pragma unroll
  for (int s = 0; s < 4; ++s) {
    float4 bb = b4[s];
    float4 xx = p2x[s], yy = p2y[s], zz = p2z[s];
    float w0 = kf[s * 4 + 0] * bb.x;
    float w1 = kf[s * 4 + 1] * bb.y;
    float w2 = kf[s * 4 + 2] * bb.z;
    float w3 = kf[s * 4 + 3] * bb.w;
    S += (w0 + w1) + (w2 + w3);
    Sx += w0 * xx.x + w1 * xx.y + w2 * xx.z + w3 * xx.w;
    Sy += w0 * yy.x + w1 * yy.y + w2 * yy.z + w3 * yy.w;
    Sz += w0 * zz.x + w1 * zz.y + w2 * zz.z + w3 * zz.w;
  }
#pragma unroll
  for (int off = 32; off; off >>= 1) {
    S  += __shfl_down(S, off, 64);
    Sx += __shfl_down(Sx, off, 64);
    Sy += __shfl_down(Sy, off, 64);
    Sz += __shfl_down(Sz, off, 64);
  }
  __shared__ float red[4][4];
  int lane = threadIdx.x & 63, wid = threadIdx.x >> 6;
  if (lane == 0) {
    red[wid][0] = S; red[wid][1] = Sx; red[wid][2] = Sy; red[wid][3] = Sz;
  }
  __syncthreads();
  if (threadIdx.x == 0) {
    float kb  = red[0][0] + red[1][0] + red[2][0] + red[3][0];
    float Sxt = red[0][1] + red[1][1] + red[2][1] + red[3][1];
    float Syt = red[0][2] + red[1][2] + red[2][2] + red[3][2];
    float Szt = red[0][3] + red[1][3] + red[2][3] + red[3][3];
    float eps = expf(g_eps[0]) + 0.03f;
    float gam = expf(g_gamma[0]) + 0.03f;
    float power = gam / (gam + eps);
    float av = powf((1.0f / NN) / (kb + 1e-8f), power);
    float denom = av * kb + 1e-6f;
    const float* p1 = pc1 + (size_t)b * 3 * NN;
    size_t o = ((size_t)b * NN + i) * 3;
    out[o + 0] = av * Sxt / denom - p1[0 * NN + i];
    out[o + 1] = av * Syt / denom - p1[1 * NN + i];
    out[o + 2] = av * Szt / denom - p1[2 * NN + i];
  }
}

// ---------------------------------------------------------------------------
extern "C" void kernel_launch(void* const* d_in, const int* in_sizes, int n_in,
                              void* d_out, int out_size, void* d_ws,
                              size_t ws_size, hipStream_t stream) {
  const float* pc1 = (const float*)d_in[0];
  const float* pc2 = (const float*)d_in[1];
  const float* f1 = (const float*)d_in[2];
  const float* f2 = (const float*)d_in[3];
  const float* g_gamma = (const float*)d_in[4];
  const float* g_eps = (const float*)d_in[5];
  float* out = (float*)d_out;

  // Workspace layout
  size_t off = 0;
  char* ws = (char*)d_ws;
  unsigned char* K = (unsigned char*)(ws + off);
  off += (size_t)NB * NN * NN * sizeof(unsigned char);                             // 33.5 MB
  __half* f1t = (__half*)(ws + off); off += (size_t)NB * NN * NC * sizeof(__half); // 4 MB
  __half* f2t = (__half*)(ws + off); off += (size_t)NB * NN * NC * sizeof(__half); // 4 MB
  float* inv1 = (float*)(ws + off); off += (size_t)NB * NN * sizeof(float);
  float* inv2 = (float*)(ws + off); off += (size_t)NB * NN * sizeof(float);
  float* bvec = (float*)(ws + off); off += (size_t)NB * NN * sizeof(float);
  float* part = (float*)(ws + off); off += (size_t)PBLOCKS * NN * sizeof(float);   // 8 MB
  if (ws_size < off) return;  // workspace too small

  norms_kernel<<<dim3(NN / 256, NB, 2), 256, 0, stream>>>(f1, f2, inv1, inv2);
  prep_kernel<<<dim3(NN / 64, NC / 64, NB * 2), 256, 0, stream>>>(
      f1, f2, inv1, inv2, f1t, f2t);
  kmat_mfma_kernel<<<dim3(NN / 128, NN / 128, NB), 256, 0, stream>>>(
      f1t, f2t, pc1, pc2, g_eps, K);

  for (int it = 0; it < MAX_ITER; ++it) {
    fused_pass_kernel<<<dim3(PBLOCKS), 512, 0, stream>>>(
        K, bvec, part, g_gamma, g_eps, it);
    breduce_kernel<<<dim3(NN / 64, NB), 256, 0, stream>>>(
        part, bvec, g_gamma, g_eps);
  }

  kb_flow_kernel<<<dim3(NN, NB), 256, 0, stream>>>(K, bvec, pc1, pc2,
                                                   g_gamma, g_eps, out);
}

// Round 10
// 348.048 us; speedup vs baseline: 1.1570x; 1.1570x over previous
//
#include <hip/hip_runtime.h>
#include <hip/hip_fp16.h>
#include <math.h>

// Problem constants (from setup_inputs): B=2, C=256, N=4096
#define NB 2
#define NC 256
#define NN 4096
#define MAX_ITER 10

#define PBLOCKS 512                    // fused-pass blocks (256 per batch)
#define PCHUNKS 256                    // partial chunks per batch
#define PROWS 16                       // rows per fused-pass block (4 per wave)

#define BK 32                          // K-step (R10: was 64; halves stage LDS)
#define LDA 40                         // padded LDS row stride in halfs
                                       // (80 B rows: 16B-aligned; 8-bank read
                                       // pattern same as proven LDA=72 layout)
#define C8S 144                        // padded C8 byte stride

typedef _Float16 half8_t __attribute__((ext_vector_type(8)));
typedef float f32x4 __attribute__((ext_vector_type(4)));
typedef float f32x2 __attribute__((ext_vector_type(2)));

// Decode 16 fp8 (e4m3, packed in uint4) -> 16 floats. HW cvt, gfx950.
__device__ inline void fp8x16_decode(uint4 v, float* o) {
  f32x2 p;
  p = __builtin_amdgcn_cvt_pk_f32_fp8(v.x, false); o[0] = p[0];  o[1] = p[1];
  p = __builtin_amdgcn_cvt_pk_f32_fp8(v.x, true);  o[2] = p[0];  o[3] = p[1];
  p = __builtin_amdgcn_cvt_pk_f32_fp8(v.y, false); o[4] = p[0];  o[5] = p[1];
  p = __builtin_amdgcn_cvt_pk_f32_fp8(v.y, true);  o[6] = p[0];  o[7] = p[1];
  p = __builtin_amdgcn_cvt_pk_f32_fp8(v.z, false); o[8] = p[0];  o[9] = p[1];
  p = __builtin_amdgcn_cvt_pk_f32_fp8(v.z, true);  o[10] = p[0]; o[11] = p[1];
  p = __builtin_amdgcn_cvt_pk_f32_fp8(v.w, false); o[12] = p[0]; o[13] = p[1];
  p = __builtin_amdgcn_cvt_pk_f32_fp8(v.w, true);  o[14] = p[0]; o[15] = p[1];
}

// ---------------------------------------------------------------------------
// 1) inv_norm[b,n] = 1/sqrt(sum_c feats[b,c,n]^2 + 1e-6)
__global__ __launch_bounds__(256) void norms_kernel(
    const float* __restrict__ f1, const float* __restrict__ f2,
    float* __restrict__ inv1, float* __restrict__ inv2) {
  int n = blockIdx.x * 256 + threadIdx.x;
  int b = blockIdx.y;
  const float* f = blockIdx.z ? f2 : f1;
  float* o = blockIdx.z ? inv2 : inv1;
  const float* base = f + (size_t)b * NC * NN + n;
  float s = 0.f;
#pragma unroll 8
  for (int c = 0; c < NC; ++c) {
    float v = base[(size_t)c * NN];
    s = fmaf(v, v, s);
  }
  o[b * NN + n] = 1.0f / sqrtf(s + 1e-6f);
}

// ---------------------------------------------------------------------------
// 1b) prep: f_t[b][n][c] = f[b][c][n] * inv[b][n], cast to f16.
__global__ __launch_bounds__(256) void prep_kernel(
    const float* __restrict__ f1, const float* __restrict__ f2,
    const float* __restrict__ inv1, const float* __restrict__ inv2,
    __half* __restrict__ f1t, __half* __restrict__ f2t) {
  int which = blockIdx.z & 1;
  int b = blockIdx.z >> 1;
  const float* f = which ? f2 : f1;
  const float* inv = which ? inv2 : inv1;
  __half* ft = which ? f2t : f1t;
  int n0 = blockIdx.x * 64;
  int c0 = blockIdx.y * 64;

  __shared__ float T[64][65];
  int t = threadIdx.x;
  int lane = t & 63, grp = t >> 6;
#pragma unroll
  for (int p = 0; p < 16; ++p) {
    int c_in = p * 4 + grp;
    T[lane][c_in] = f[((size_t)b * NC + c0 + c_in) * NN + n0 + lane];
  }
  __syncthreads();
#pragma unroll
  for (int p = 0; p < 16; ++p) {
    int n_out = p * 4 + grp;
    float v = T[n_out][lane] * inv[b * NN + n0 + n_out];
    ft[((size_t)b * NN + n0 + n_out) * NC + c0 + lane] = __float2half(v);
  }
}

// ---------------------------------------------------------------------------
// 2) K[b,i,j] = exp((corr-1)/eps') * (dist < 0.25) via f16 MFMA, fp8 store.
// R10: BK 64->32. Counters showed kmat latency-bound at 2 blocks/CU
// (Occupancy 26%, MfmaUtil 12%, HBM 1 TB/s — none near a roof). Stage LDS
// drops 36.9 KB -> 20 KB; total 24 KB -> 6 blocks/CU (3x TLP) so other
// blocks' MFMAs hide each block's load->barrier latency. Same total load
// traffic (8 steps x 4 uint4 = 4 x 8), same coalescing, K-accumulation
// order bit-identical (ascending k). Staging regs live only between the
// two barriers — no cross-barrier liveness (R7 spill law respected).
struct __align__(16) SMstage { __half A[128 * LDA]; __half B[128 * LDA]; };
union SMu { SMstage st; unsigned char C8[128 * C8S]; };

__global__ __launch_bounds__(256) void kmat_mfma_kernel(
    const __half* __restrict__ f1t, const __half* __restrict__ f2t,
    const float* __restrict__ pc1, const float* __restrict__ pc2,
    const float* __restrict__ g_eps, unsigned char* __restrict__ K) {
  int b = blockIdx.z;
  int i0 = blockIdx.y * 128;
  int j0 = blockIdx.x * 128;

  __shared__ SMu sm;
  __shared__ float p1s[4][128];
  __shared__ float p2s[4][128];

  int tid = threadIdx.x;
  if (tid < 128) {
    int i = i0 + tid;
    float x = pc1[((size_t)b * 3 + 0) * NN + i];
    float y = pc1[((size_t)b * 3 + 1) * NN + i];
    float z = pc1[((size_t)b * 3 + 2) * NN + i];
    p1s[0][tid] = x; p1s[1][tid] = y; p1s[2][tid] = z;
    p1s[3][tid] = x * x + y * y + z * z;
  } else {
    int j = j0 + tid - 128;
    float x = pc2[((size_t)b * 3 + 0) * NN + j];
    float y = pc2[((size_t)b * 3 + 1) * NN + j];
    float z = pc2[((size_t)b * 3 + 2) * NN + j];
    p2s[0][tid - 128] = x; p2s[1][tid - 128] = y; p2s[2][tid - 128] = z;
    p2s[3][tid - 128] = x * x + y * y + z * z;
  }
  float inv_eps = 1.0f / (expf(g_eps[0]) + 0.03f);

  const __half* Ag = f1t + ((size_t)b * NN + i0) * NC;
  const __half* Bg = f2t + ((size_t)b * NN + j0) * NC;

  int lane = tid & 63, wid = tid >> 6;
  int m0 = (wid >> 1) * 64, n0 = (wid & 1) * 64;
  int l15 = lane & 15, quad = lane >> 4;

  f32x4 acc[4][4] = {};

  // Staging map: 2 threads per row; thread covers 32 B (2 uint4) of the
  // row's 64 B K-slice. sr = row, sh = which 32 B half.
  int sr = tid >> 1, sh = tid & 1;

  for (int kk = 0; kk < NC; kk += BK) {
    __syncthreads();
    {
      const uint4* As = (const uint4*)(Ag + (size_t)sr * NC + kk + sh * 16);
      const uint4* Bs = (const uint4*)(Bg + (size_t)sr * NC + kk + sh * 16);
      uint4* Ad = (uint4*)&sm.st.A[sr * LDA + sh * 16];
      uint4* Bd = (uint4*)&sm.st.B[sr * LDA + sh * 16];
      Ad[0] = As[0]; Ad[1] = As[1];
      Bd[0] = Bs[0]; Bd[1] = Bs[1];
    }
    __syncthreads();
    {
      half8_t aF[4], bF[4];
#pragma unroll
      for (int mt = 0; mt < 4; ++mt)
        aF[mt] = *(const half8_t*)&sm.st.A[(m0 + mt * 16 + l15) * LDA + quad * 8];
#pragma unroll
      for (int nt = 0; nt < 4; ++nt)
        bF[nt] = *(const half8_t*)&sm.st.B[(n0 + nt * 16 + l15) * LDA + quad * 8];
#pragma unroll
      for (int mt = 0; mt < 4; ++mt)
#pragma unroll
        for (int nt = 0; nt < 4; ++nt)
          acc[mt][nt] = __builtin_amdgcn_mfma_f32_16x16x32_f16(
              aF[mt], bF[nt], acc[mt][nt], 0, 0, 0);
    }
  }

  __syncthreads();

  float c2x[4], c2y[4], c2z[4], c2n[4];
#pragma unroll
  for (int nt = 0; nt < 4; ++nt) {
    int c = n0 + nt * 16 + l15;
    c2x[nt] = p2s[0][c]; c2y[nt] = p2s[1][c];
    c2z[nt] = p2s[2][c]; c2n[nt] = p2s[3][c];
  }
#pragma unroll
  for (int mt = 0; mt < 4; ++mt) {
#pragma unroll
    for (int rr = 0; rr < 4; ++rr) {
      int row = m0 + mt * 16 + quad * 4 + rr;
      float px = p1s[0][row], py = p1s[1][row], pz = p1s[2][row];
      float n1 = p1s[3][row];
#pragma unroll
      for (int nt = 0; nt < 4; ++nt) {
        float corr = acc[mt][nt][rr];
        float dist = n1 + c2n[nt] - 2.0f * (px * c2x[nt] + py * c2y[nt] + pz * c2z[nt]);
        float kv = (dist < 0.25f) ? __expf((corr - 1.0f) * inv_eps) : 0.0f;
        unsigned int pk = (unsigned int)__builtin_amdgcn_cvt_pk_fp8_f32(kv, kv, 0, false);
        sm.C8[row * C8S + n0 + nt * 16 + l15] = (unsigned char)(pk & 0xFF);
      }
    }
  }
  __syncthreads();

  // Coalesced fp8 store: 8 threads cover a 128B row, 32 rows per sweep.
  int c8 = tid & 7, rg = tid >> 3;
#pragma unroll
  for (int s = 0; s < 4; ++s) {
    int row = s * 32 + rg;
    uint4 v = *(uint4*)&sm.C8[row * C8S + c8 * 16];
    *(uint4*)&K[((size_t)b * NN + i0 + row) * NN + j0 + c8 * 16] = v;
  }
}

// ---------------------------------------------------------------------------
// 3) Fused Sinkhorn pass over fp8 K. R6's proven two-phase structure
// (350.6 µs total), byte-identical:
//   Phase 1 (row-split): wave w computes dots for its 4 rows (kraw + per-q
//     b slices, R0's chain order), wgt broadcast via 64 B LDS.
//   Phase 2 (column-split): wave w re-reads its 1024-col quarter of all 16
//     rows (L2-hot), ps[16] -> part[g][quarter] directly. No 64 KB reduce.
// No launch_bounds cap (R4/R5 spill law).
__global__ __launch_bounds__(256) void fused_pass_kernel(
    const unsigned char* __restrict__ K, const float* __restrict__ bvec,
    float* __restrict__ part, const float* __restrict__ g_gamma,
    const float* __restrict__ g_eps, int pass) {
  __shared__ float wgt_s[PROWS];  // 64 B

  int g = blockIdx.x;            // 0..511
  int batch = g >> 8;
  int row0 = (g & 255) * PROWS;
  int tid = threadIdx.x;
  int w = tid >> 6, l = tid & 63;
  const unsigned char* Kb = K + (size_t)batch * NN * NN;

  float eps = expf(g_eps[0]) + 0.03f;
  float gam = expf(g_gamma[0]) + 0.03f;
  float power = gam / (gam + eps);
  const float probN = 1.0f / NN;

  if (pass > 0) {
    int rbase = row0 + w * 4;  // 4 rows per wave

    // Load the wave's 4 rows (full width): 16 independent 16B loads.
    uint4 kraw[4][4];
#pragma unroll
    for (int r = 0; r < 4; ++r) {
      const uint4* Kr = (const uint4*)(Kb + (size_t)(rbase + r) * NN);
#pragma unroll
      for (int q = 0; q < 4; ++q) kraw[r][q] = Kr[q * 64 + l];
    }

    // Dots: q outer (16-float b slice live at a time), r inner. Chain
    // order (q-major, s-minor) identical to R0's proven body.
    float d0[4] = {}, d1[4] = {}, d2[4] = {}, d3[4] = {};
#pragma unroll
    for (int q = 0; q < 4; ++q) {
      float bq[16];
      const float4* bp = (const float4*)&bvec[batch * NN + (q * 64 + l) * 16];
#pragma unroll
      for (int s = 0; s < 4; ++s) {
        float4 bb = bp[s];
        bq[s * 4 + 0] = bb.x; bq[s * 4 + 1] = bb.y;
        bq[s * 4 + 2] = bb.z; bq[s * 4 + 3] = bb.w;
      }
#pragma unroll
      for (int r = 0; r < 4; ++r) {
        float kf[16];
        fp8x16_decode(kraw[r][q], kf);
#pragma unroll
        for (int s = 0; s < 4; ++s) {
          d0[r] = fmaf(kf[s * 4 + 0], bq[s * 4 + 0], d0[r]);
          d1[r] = fmaf(kf[s * 4 + 1], bq[s * 4 + 1], d1[r]);
          d2[r] = fmaf(kf[s * 4 + 2], bq[s * 4 + 2], d2[r]);
          d3[r] = fmaf(kf[s * 4 + 3], bq[s * 4 + 3], d3[r]);
        }
      }
    }
    // Serial per-row tree + powf (R0's proven pattern).
#pragma unroll
    for (int r = 0; r < 4; ++r) {
      float kbs = (d0[r] + d1[r]) + (d2[r] + d3[r]);
#pragma unroll
      for (int off = 1; off < 64; off <<= 1) kbs += __shfl_xor(kbs, off, 64);
      if (l == 0) wgt_s[w * 4 + r] = __powf(probN / (kbs + 1e-8f), power);
    }
  }

  // Keep phase-2 loads out of phase-1's register peak.
  __builtin_amdgcn_sched_barrier(0);

  // Phase 2: wave w reads ALL 16 rows over its 1024-col quarter
  // (L2-hot: this CU just read those rows in phase 1).
  uint4 k2[PROWS];
#pragma unroll
  for (int r = 0; r < PROWS; ++r)
    k2[r] = *(const uint4*)(Kb + (size_t)(row0 + r) * NN + w * 1024 + l * 16);

  if (pass > 0) __syncthreads();  // wgt_s ready (load latency hides here)

  float ps[16];
#pragma unroll
  for (int e = 0; e < 16; ++e) ps[e] = 0.f;
#pragma unroll
  for (int r = 0; r < PROWS; ++r) {
    float wr = (pass == 0) ? probN : wgt_s[r];
    float kf[16];
    fp8x16_decode(k2[r], kf);
#pragma unroll
    for (int e = 0; e < 16; ++e) ps[e] = fmaf(kf[e], wr, ps[e]);
  }

  // Store: wave w's quarter of part[g][:] (16 B/lane per store, 4 stores).
  float* pout = &part[(size_t)g * NN + w * 1024 + l * 16];
#pragma unroll
  for (int s = 0; s < 4; ++s)
    *(float4*)&pout[s * 4] = make_float4(ps[s * 4 + 0], ps[s * 4 + 1],
                                         ps[s * 4 + 2], ps[s * 4 + 3]);
}

// ---------------------------------------------------------------------------
// 3b) b[j] = (probN / (sum_k part[b,k,j] + 1e-8))^power
// 64 cols x 4 k-slices per block; grid (NN/64, NB) = 128 blocks.
__global__ __launch_bounds__(256) void breduce_kernel(
    const float* __restrict__ part, float* __restrict__ bvec,
    const float* __restrict__ g_gamma, const float* __restrict__ g_eps) {
  int b = blockIdx.y;
  int c0 = blockIdx.x * 64;
  int t = threadIdx.x;
  int cl = t & 63, kg = t >> 6;
  const float* p = part + (size_t)(b * PCHUNKS + kg * 64) * NN + c0 + cl;
  float s = 0.f;
#pragma unroll 8
  for (int k = 0; k < 64; ++k) s += p[(size_t)k * NN];
  __shared__ float red[4][64];
  red[kg][cl] = s;
  __syncthreads();
  if (t < 64) {
    float tot = (red[0][t] + red[1][t]) + (red[2][t] + red[3][t]);
    float eps = expf(g_eps[0]) + 0.03f;
    float gam = expf(g_gamma[0]) + 0.03f;
    float power = gam / (gam + eps);
    bvec[b * NN + c0 + t] = __powf((1.0f / NN) / (tot + 1e-8f), power);
  }
}

// ---------------------------------------------------------------------------
// 4) Final pass fused: Kb + Sxyz, then a_10 and flow. fp8 K.
__global__ __launch_bounds__(256) void kb_flow_kernel(
    const unsigned char* __restrict__ K, const float* __restrict__ bvec,
    const float* __restrict__ pc1, const float* __restrict__ pc2,
    const float* __restrict__ g_gamma, const float* __restrict__ g_eps,
    float* __restrict__ out) {
  int b = blockIdx.y;
  int i = blockIdx.x;
  int j16 = threadIdx.x;  // 0..255
  const uint4* K16 = (const uint4*)(K + ((size_t)b * NN + i) * NN);
  uint4 kv = K16[j16];
  float kf[16];
  fp8x16_decode(kv, kf);

  const float4* b4 = (const float4*)&bvec[b * NN + j16 * 16];
  const float* p2 = pc2 + (size_t)b * 3 * NN;
  const float4* p2x = (const float4*)&p2[0 * NN + j16 * 16];
  const float4* p2y = (const float4*)&p2[1 * NN + j16 * 16];
  const float4* p2z = (const float4*)&p2[2 * NN + j16 * 16];

  float S = 0.f, Sx = 0.f, Sy = 0.f, Sz = 0.f;
#pragma unroll
  for (int s = 0; s < 4; ++s) {
    float4 bb = b4[s];
    float4 xx = p2x[s], yy = p2y[s], zz = p2z[s];
    float w0 = kf[s * 4 + 0] * bb.x;
    float w1 = kf[s * 4 + 1] * bb.y;
    float w2 = kf[s * 4 + 2] * bb.z;
    float w3 = kf[s * 4 + 3] * bb.w;
    S += (w0 + w1) + (w2 + w3);
    Sx += w0 * xx.x + w1 * xx.y + w2 * xx.z + w3 * xx.w;
    Sy += w0 * yy.x + w1 * yy.y + w2 * yy.z + w3 * yy.w;
    Sz += w0 * zz.x + w1 * zz.y + w2 * zz.z + w3 * zz.w;
  }
#pragma unroll
  for (int off = 32; off; off >>= 1) {
    S  += __shfl_down(S, off, 64);
    Sx += __shfl_down(Sx, off, 64);
    Sy += __shfl_down(Sy, off, 64);
    Sz += __shfl_down(Sz, off, 64);
  }
  __shared__ float red[4][4];
  int lane = threadIdx.x & 63, wid = threadIdx.x >> 6;
  if (lane == 0) {
    red[wid][0] = S; red[wid][1] = Sx; red[wid][2] = Sy; red[wid][3] = Sz;
  }
  __syncthreads();
  if (threadIdx.x == 0) {
    float kb  = red[0][0] + red[1][0] + red[2][0] + red[3][0];
    float Sxt = red[0][1] + red[1][1] + red[2][1] + red[3][1];
    float Syt = red[0][2] + red[1][2] + red[2][2] + red[3][2];
    float Szt = red[0][3] + red[1][3] + red[2][3] + red[3][3];
    float eps = expf(g_eps[0]) + 0.03f;
    float gam = expf(g_gamma[0]) + 0.03f;
    float power = gam / (gam + eps);
    float av = powf((1.0f / NN) / (kb + 1e-8f), power);
    float denom = av * kb + 1e-6f;
    const float* p1 = pc1 + (size_t)b * 3 * NN;
    size_t o = ((size_t)b * NN + i) * 3;
    out[o + 0] = av * Sxt / denom - p1[0 * NN + i];
    out[o + 1] = av * Syt / denom - p1[1 * NN + i];
    out[o + 2] = av * Szt / denom - p1[2 * NN + i];
  }
}

// ---------------------------------------------------------------------------
extern "C" void kernel_launch(void* const* d_in, const int* in_sizes, int n_in,
                              void* d_out, int out_size, void* d_ws,
                              size_t ws_size, hipStream_t stream) {
  const float* pc1 = (const float*)d_in[0];
  const float* pc2 = (const float*)d_in[1];
  const float* f1 = (const float*)d_in[2];
  const float* f2 = (const float*)d_in[3];
  const float* g_gamma = (const float*)d_in[4];
  const float* g_eps = (const float*)d_in[5];
  float* out = (float*)d_out;

  // Workspace layout
  size_t off = 0;
  char* ws = (char*)d_ws;
  unsigned char* K = (unsigned char*)(ws + off);
  off += (size_t)NB * NN * NN * sizeof(unsigned char);                             // 33.5 MB
  __half* f1t = (__half*)(ws + off); off += (size_t)NB * NN * NC * sizeof(__half); // 4 MB
  __half* f2t = (__half*)(ws + off); off += (size_t)NB * NN * NC * sizeof(__half); // 4 MB
  float* inv1 = (float*)(ws + off); off += (size_t)NB * NN * sizeof(float);
  float* inv2 = (float*)(ws + off); off += (size_t)NB * NN * sizeof(float);
  float* bvec = (float*)(ws + off); off += (size_t)NB * NN * sizeof(float);
  float* part = (float*)(ws + off); off += (size_t)PBLOCKS * NN * sizeof(float);   // 8 MB
  if (ws_size < off) return;  // workspace too small

  norms_kernel<<<dim3(NN / 256, NB, 2), 256, 0, stream>>>(f1, f2, inv1, inv2);
  prep_kernel<<<dim3(NN / 64, NC / 64, NB * 2), 256, 0, stream>>>(
      f1, f2, inv1, inv2, f1t, f2t);
  kmat_mfma_kernel<<<dim3(NN / 128, NN / 128, NB), 256, 0, stream>>>(
      f1t, f2t, pc1, pc2, g_eps, K);

  for (int it = 0; it < MAX_ITER; ++it) {
    fused_pass_kernel<<<dim3(PBLOCKS), 256, 0, stream>>>(
        K, bvec, part, g_gamma, g_eps, it);
    breduce_kernel<<<dim3(NN / 64, NB), 256, 0, stream>>>(
        part, bvec, g_gamma, g_eps);
  }

  kb_flow_kernel<<<dim3(NN, NB), 256, 0, stream>>>(K, bvec, pc1, pc2,
                                                   g_gamma, g_eps, out);
}

// Round 11
// 332.277 us; speedup vs baseline: 1.2119x; 1.0475x over previous
//
#include <hip/hip_runtime.h>
#include <hip/hip_fp16.h>
#include <math.h>

// Problem constants (from setup_inputs): B=2, C=256, N=4096
#define NB 2
#define NC 256
#define NN 4096
#define MAX_ITER 10

#define PBLOCKS 512                    // fused-pass blocks (256 per batch)
#define PCHUNKS 256                    // partial chunks per batch
#define PROWS 16                       // rows per fused-pass block (2 per wave)

#define BK 32                          // K-step (halfs)
#define LDA 40                         // padded LDS row stride in halfs (80 B)
#define C8S 144                        // padded C8 byte stride

typedef _Float16 half8_t __attribute__((ext_vector_type(8)));
typedef float f32x4 __attribute__((ext_vector_type(4)));
typedef float f32x2 __attribute__((ext_vector_type(2)));

// Decode 16 fp8 (e4m3, packed in uint4) -> 16 floats. HW cvt, gfx950.
__device__ inline void fp8x16_decode(uint4 v, float* o) {
  f32x2 p;
  p = __builtin_amdgcn_cvt_pk_f32_fp8(v.x, false); o[0] = p[0];  o[1] = p[1];
  p = __builtin_amdgcn_cvt_pk_f32_fp8(v.x, true);  o[2] = p[0];  o[3] = p[1];
  p = __builtin_amdgcn_cvt_pk_f32_fp8(v.y, false); o[4] = p[0];  o[5] = p[1];
  p = __builtin_amdgcn_cvt_pk_f32_fp8(v.y, true);  o[6] = p[0];  o[7] = p[1];
  p = __builtin_amdgcn_cvt_pk_f32_fp8(v.z, false); o[8] = p[0];  o[9] = p[1];
  p = __builtin_amdgcn_cvt_pk_f32_fp8(v.z, true);  o[10] = p[0]; o[11] = p[1];
  p = __builtin_amdgcn_cvt_pk_f32_fp8(v.w, false); o[12] = p[0]; o[13] = p[1];
  p = __builtin_amdgcn_cvt_pk_f32_fp8(v.w, true);  o[14] = p[0]; o[15] = p[1];
}

// Decode 8 fp8 (e4m3, packed in uint2) -> 8 floats.
__device__ inline void fp8x8_decode(uint2 v, float* o) {
  f32x2 p;
  p = __builtin_amdgcn_cvt_pk_f32_fp8(v.x, false); o[0] = p[0]; o[1] = p[1];
  p = __builtin_amdgcn_cvt_pk_f32_fp8(v.x, true);  o[2] = p[0]; o[3] = p[1];
  p = __builtin_amdgcn_cvt_pk_f32_fp8(v.y, false); o[4] = p[0]; o[5] = p[1];
  p = __builtin_amdgcn_cvt_pk_f32_fp8(v.y, true);  o[6] = p[0]; o[7] = p[1];
}

// ---------------------------------------------------------------------------
// 1) inv_norm[b,n] = 1/sqrt(sum_c feats[b,c,n]^2 + 1e-6)
__global__ __launch_bounds__(256) void norms_kernel(
    const float* __restrict__ f1, const float* __restrict__ f2,
    float* __restrict__ inv1, float* __restrict__ inv2) {
  int n = blockIdx.x * 256 + threadIdx.x;
  int b = blockIdx.y;
  const float* f = blockIdx.z ? f2 : f1;
  float* o = blockIdx.z ? inv2 : inv1;
  const float* base = f + (size_t)b * NC * NN + n;
  float s = 0.f;
#pragma unroll 8
  for (int c = 0; c < NC; ++c) {
    float v = base[(size_t)c * NN];
    s = fmaf(v, v, s);
  }
  o[b * NN + n] = 1.0f / sqrtf(s + 1e-6f);
}

// ---------------------------------------------------------------------------
// 1b) prep: f_t[b][n][c] = f[b][c][n] * inv[b][n], cast to f16.
__global__ __launch_bounds__(256) void prep_kernel(
    const float* __restrict__ f1, const float* __restrict__ f2,
    const float* __restrict__ inv1, const float* __restrict__ inv2,
    __half* __restrict__ f1t, __half* __restrict__ f2t) {
  int which = blockIdx.z & 1;
  int b = blockIdx.z >> 1;
  const float* f = which ? f2 : f1;
  const float* inv = which ? inv2 : inv1;
  __half* ft = which ? f2t : f1t;
  int n0 = blockIdx.x * 64;
  int c0 = blockIdx.y * 64;

  __shared__ float T[64][65];
  int t = threadIdx.x;
  int lane = t & 63, grp = t >> 6;
#pragma unroll
  for (int p = 0; p < 16; ++p) {
    int c_in = p * 4 + grp;
    T[lane][c_in] = f[((size_t)b * NC + c0 + c_in) * NN + n0 + lane];
  }
  __syncthreads();
#pragma unroll
  for (int p = 0; p < 16; ++p) {
    int n_out = p * 4 + grp;
    float v = T[n_out][lane] * inv[b * NN + n0 + n_out];
    ft[((size_t)b * NN + n0 + n_out) * NC + c0 + lane] = __float2half(v);
  }
}

// ---------------------------------------------------------------------------
// 2) K[b,i,j] = exp((corr-1)/eps') * (dist < 0.25) via f16 MFMA, fp8 store.
// R11: LDS DOUBLE-BUFFER (T14 async-stage, spill-safe). R10 showed kmat is
// NOT LDS-occupancy-bound (24KB, occupancy flat, dur flat): the cost is the
// serialized load->barrier->MFMA chain (~4000 cyc/K-step). Now step t+1's
// loads issue right after the barrier, MFMAs on buf[cur] run WITHOUT waiting
// on them, then regs are written to buf[cur^1] before the single barrier.
// Staging regs cross ZERO barriers (R7's spill was cross-barrier liveness).
// One barrier per step (was 2). LDS: 2x20KB stage + C8 union ~45KB.
struct __align__(16) SMstage { __half A[2][128 * LDA]; __half B[2][128 * LDA]; };
union SMu { SMstage st; unsigned char C8[128 * C8S]; };

__global__ __launch_bounds__(256) void kmat_mfma_kernel(
    const __half* __restrict__ f1t, const __half* __restrict__ f2t,
    const float* __restrict__ pc1, const float* __restrict__ pc2,
    const float* __restrict__ g_eps, unsigned char* __restrict__ K) {
  int b = blockIdx.z;
  int i0 = blockIdx.y * 128;
  int j0 = blockIdx.x * 128;

  __shared__ SMu sm;
  __shared__ float p1s[4][128];
  __shared__ float p2s[4][128];

  int tid = threadIdx.x;
  if (tid < 128) {
    int i = i0 + tid;
    float x = pc1[((size_t)b * 3 + 0) * NN + i];
    float y = pc1[((size_t)b * 3 + 1) * NN + i];
    float z = pc1[((size_t)b * 3 + 2) * NN + i];
    p1s[0][tid] = x; p1s[1][tid] = y; p1s[2][tid] = z;
    p1s[3][tid] = x * x + y * y + z * z;
  } else {
    int j = j0 + tid - 128;
    float x = pc2[((size_t)b * 3 + 0) * NN + j];
    float y = pc2[((size_t)b * 3 + 1) * NN + j];
    float z = pc2[((size_t)b * 3 + 2) * NN + j];
    p2s[0][tid - 128] = x; p2s[1][tid - 128] = y; p2s[2][tid - 128] = z;
    p2s[3][tid - 128] = x * x + y * y + z * z;
  }
  float inv_eps = 1.0f / (expf(g_eps[0]) + 0.03f);

  const __half* Ag = f1t + ((size_t)b * NN + i0) * NC;
  const __half* Bg = f2t + ((size_t)b * NN + j0) * NC;

  int lane = tid & 63, wid = tid >> 6;
  int m0 = (wid >> 1) * 64, n0 = (wid & 1) * 64;
  int l15 = lane & 15, quad = lane >> 4;

  f32x4 acc[4][4] = {};

  // Staging map: 2 threads per row; thread covers 16 halfs (2 uint4) of the
  // row's BK=32-half K-slice. sr = row, sh = which 16-half half.
  int sr = tid >> 1, sh = tid & 1;
  const __half* Arow = Ag + (size_t)sr * NC + sh * 16;
  const __half* Brow = Bg + (size_t)sr * NC + sh * 16;
  int ldoff = sr * LDA + sh * 16;

  // Prologue: stage step 0 into buf0.
  {
    uint4 a0 = ((const uint4*)Arow)[0], a1 = ((const uint4*)Arow)[1];
    uint4 b0 = ((const uint4*)Brow)[0], b1 = ((const uint4*)Brow)[1];
    uint4* Ad = (uint4*)&sm.st.A[0][ldoff];
    uint4* Bd = (uint4*)&sm.st.B[0][ldoff];
    Ad[0] = a0; Ad[1] = a1;
    Bd[0] = b0; Bd[1] = b1;
  }
  __syncthreads();

  for (int t = 0; t < NC / BK; ++t) {
    int cur = t & 1;
    // Issue step t+1's loads NOW; latency hides under the MFMAs below.
    uint4 a0, a1, b0, b1;
    if (t < NC / BK - 1) {
      const __half* An = Arow + (t + 1) * BK;
      const __half* Bn = Brow + (t + 1) * BK;
      a0 = ((const uint4*)An)[0]; a1 = ((const uint4*)An)[1];
      b0 = ((const uint4*)Bn)[0]; b1 = ((const uint4*)Bn)[1];
    }
    // MFMAs on buf[cur] — no dependency on the in-flight loads.
    {
      half8_t aF[4], bF[4];
#pragma unroll
      for (int mt = 0; mt < 4; ++mt)
        aF[mt] = *(const half8_t*)&sm.st.A[cur][(m0 + mt * 16 + l15) * LDA + quad * 8];
#pragma unroll
      for (int nt = 0; nt < 4; ++nt)
        bF[nt] = *(const half8_t*)&sm.st.B[cur][(n0 + nt * 16 + l15) * LDA + quad * 8];
#pragma unroll
      for (int mt = 0; mt < 4; ++mt)
#pragma unroll
        for (int nt = 0; nt < 4; ++nt)
          acc[mt][nt] = __builtin_amdgcn_mfma_f32_16x16x32_f16(
              aF[mt], bF[nt], acc[mt][nt], 0, 0, 0);
    }
    // Write the prefetched step into the other buffer (waits vmcnt here,
    // after the MFMAs). Regs live only within this iteration — no barrier
    // crossed -> no spill (R7 law).
    if (t < NC / BK - 1) {
      uint4* Ad = (uint4*)&sm.st.A[cur ^ 1][ldoff];
      uint4* Bd = (uint4*)&sm.st.B[cur ^ 1][ldoff];
      Ad[0] = a0; Ad[1] = a1;
      Bd[0] = b0; Bd[1] = b1;
    }
    __syncthreads();
  }

  float c2x[4], c2y[4], c2z[4], c2n[4];
#pragma unroll
  for (int nt = 0; nt < 4; ++nt) {
    int c = n0 + nt * 16 + l15;
    c2x[nt] = p2s[0][c]; c2y[nt] = p2s[1][c];
    c2z[nt] = p2s[2][c]; c2n[nt] = p2s[3][c];
  }
#pragma unroll
  for (int mt = 0; mt < 4; ++mt) {
#pragma unroll
    for (int rr = 0; rr < 4; ++rr) {
      int row = m0 + mt * 16 + quad * 4 + rr;
      float px = p1s[0][row], py = p1s[1][row], pz = p1s[2][row];
      float n1 = p1s[3][row];
#pragma unroll
      for (int nt = 0; nt < 4; ++nt) {
        float corr = acc[mt][nt][rr];
        float dist = n1 + c2n[nt] - 2.0f * (px * c2x[nt] + py * c2y[nt] + pz * c2z[nt]);
        float kv = (dist < 0.25f) ? __expf((corr - 1.0f) * inv_eps) : 0.0f;
        unsigned int pk = (unsigned int)__builtin_amdgcn_cvt_pk_fp8_f32(kv, kv, 0, false);
        sm.C8[row * C8S + n0 + nt * 16 + l15] = (unsigned char)(pk & 0xFF);
      }
    }
  }
  __syncthreads();

  // Coalesced fp8 store: 8 threads cover a 128B row, 32 rows per sweep.
  int c8 = tid & 7, rg = tid >> 3;
#pragma unroll
  for (int s = 0; s < 4; ++s) {
    int row = s * 32 + rg;
    uint4 v = *(uint4*)&sm.C8[row * C8S + c8 * 16];
    *(uint4*)&K[((size_t)b * NN + i0 + row) * NN + j0 + c8 * 16] = v;
  }
}

// ---------------------------------------------------------------------------
// 3) Fused Sinkhorn pass over fp8 K. R7's 512-thread two-phase version
// (passed in R7; ~-1 µs/pass vs 256-thread): 8 waves/block, 4 waves/SIMD.
//   Phase 1 (row-split): wave w owns 2 rows; b loaded per-q (16 floats live
//     at a time). FMA chain order (q-major, s-minor) identical to R0.
//   Phase 2 (column-split): wave w owns cols [w*512,(w+1)*512) of all 16
//     rows, uint2 loads, ps[8]; part/breduce layouts unchanged.
// No launch_bounds cap (R4/R5 spill law).
__global__ __launch_bounds__(512) void fused_pass_kernel(
    const unsigned char* __restrict__ K, const float* __restrict__ bvec,
    float* __restrict__ part, const float* __restrict__ g_gamma,
    const float* __restrict__ g_eps, int pass) {
  __shared__ float wgt_s[PROWS];  // 64 B

  int g = blockIdx.x;            // 0..511
  int batch = g >> 8;
  int row0 = (g & 255) * PROWS;
  int tid = threadIdx.x;
  int w = tid >> 6, l = tid & 63;  // w: 0..7
  const unsigned char* Kb = K + (size_t)batch * NN * NN;

  float eps = expf(g_eps[0]) + 0.03f;
  float gam = expf(g_gamma[0]) + 0.03f;
  float power = gam / (gam + eps);
  const float probN = 1.0f / NN;

  if (pass > 0) {
    int rbase = row0 + w * 2;  // 2 rows per wave

    // Load the wave's 2 rows (full width): 8 independent 16B loads.
    uint4 kraw[2][4];
#pragma unroll
    for (int r = 0; r < 2; ++r) {
      const uint4* Kr = (const uint4*)(Kb + (size_t)(rbase + r) * NN);
#pragma unroll
      for (int q = 0; q < 4; ++q) kraw[r][q] = Kr[q * 64 + l];
    }

    // Dots: q outer (16-float b slice live), r inner. Chain order (q-major,
    // s-minor) identical to R0's proven body.
    float d0[2] = {}, d1[2] = {}, d2[2] = {}, d3[2] = {};
#pragma unroll
    for (int q = 0; q < 4; ++q) {
      float bq[16];
      const float4* bp = (const float4*)&bvec[batch * NN + (q * 64 + l) * 16];
#pragma unroll
      for (int s = 0; s < 4; ++s) {
        float4 bb = bp[s];
        bq[s * 4 + 0] = bb.x; bq[s * 4 + 1] = bb.y;
        bq[s * 4 + 2] = bb.z; bq[s * 4 + 3] = bb.w;
      }
#pragma unroll
      for (int r = 0; r < 2; ++r) {
        float kf[16];
        fp8x16_decode(kraw[r][q], kf);
#pragma unroll
        for (int s = 0; s < 4; ++s) {
          d0[r] = fmaf(kf[s * 4 + 0], bq[s * 4 + 0], d0[r]);
          d1[r] = fmaf(kf[s * 4 + 1], bq[s * 4 + 1], d1[r]);
          d2[r] = fmaf(kf[s * 4 + 2], bq[s * 4 + 2], d2[r]);
          d3[r] = fmaf(kf[s * 4 + 3], bq[s * 4 + 3], d3[r]);
        }
      }
    }
    // Serial per-row tree + powf (R0's proven pattern).
#pragma unroll
    for (int r = 0; r < 2; ++r) {
      float kbs = (d0[r] + d1[r]) + (d2[r] + d3[r]);
#pragma unroll
      for (int off = 1; off < 64; off <<= 1) kbs += __shfl_xor(kbs, off, 64);
      if (l == 0) wgt_s[w * 2 + r] = __powf(probN / (kbs + 1e-8f), power);
    }
  }

  // Keep phase-2 loads out of phase-1's register peak.
  __builtin_amdgcn_sched_barrier(0);

  // Phase 2 loads: wave w reads ALL 16 rows over its 512-col slice
  // (L2-hot for pass>0). 16 independent 8B loads.
  uint2 k2[PROWS];
#pragma unroll
  for (int r = 0; r < PROWS; ++r)
    k2[r] = *(const uint2*)(Kb + (size_t)(row0 + r) * NN + w * 512 + l * 8);

  if (pass > 0) __syncthreads();  // wgt_s ready (load latency hides here)

  float ps[8];
#pragma unroll
  for (int e = 0; e < 8; ++e) ps[e] = 0.f;
#pragma unroll
  for (int r = 0; r < PROWS; ++r) {
    float wr = (pass == 0) ? probN : wgt_s[r];
    float kf[8];
    fp8x8_decode(k2[r], kf);
#pragma unroll
    for (int e = 0; e < 8; ++e) ps[e] = fmaf(kf[e], wr, ps[e]);
  }

  // Store: wave w's 512-col slice of part[g][:] (2 x 16B per lane).
  float* pout = &part[(size_t)g * NN + w * 512 + l * 8];
  *(float4*)&pout[0] = make_float4(ps[0], ps[1], ps[2], ps[3]);
  *(float4*)&pout[4] = make_float4(ps[4], ps[5], ps[6], ps[7]);
}

// ---------------------------------------------------------------------------
// 3b) b[j] = (probN / (sum_k part[b,k,j] + 1e-8))^power
// 64 cols x 4 k-slices per block; grid (NN/64, NB) = 128 blocks.
__global__ __launch_bounds__(256) void breduce_kernel(
    const float* __restrict__ part, float* __restrict__ bvec,
    const float* __restrict__ g_gamma, const float* __restrict__ g_eps) {
  int b = blockIdx.y;
  int c0 = blockIdx.x * 64;
  int t = threadIdx.x;
  int cl = t & 63, kg = t >> 6;
  const float* p = part + (size_t)(b * PCHUNKS + kg * 64) * NN + c0 + cl;
  float s = 0.f;
#pragma unroll 8
  for (int k = 0; k < 64; ++k) s += p[(size_t)k * NN];
  __shared__ float red[4][64];
  red[kg][cl] = s;
  __syncthreads();
  if (t < 64) {
    float tot = (red[0][t] + red[1][t]) + (red[2][t] + red[3][t]);
    float eps = expf(g_eps[0]) + 0.03f;
    float gam = expf(g_gamma[0]) + 0.03f;
    float power = gam / (gam + eps);
    bvec[b * NN + c0 + t] = __powf((1.0f / NN) / (tot + 1e-8f), power);
  }
}

// ---------------------------------------------------------------------------
// 4) Final pass fused: Kb + Sxyz, then a_10 and flow. fp8 K.
__global__ __launch_bounds__(256) void kb_flow_kernel(
    const unsigned char* __restrict__ K, const float* __restrict__ bvec,
    const float* __restrict__ pc1, const float* __restrict__ pc2,
    const float* __restrict__ g_gamma, const float* __restrict__ g_eps,
    float* __restrict__ out) {
  int b = blockIdx.y;
  int i = blockIdx.x;
  int j16 = threadIdx.x;  // 0..255
  const uint4* K16 = (const uint4*)(K + ((size_t)b * NN + i) * NN);
  uint4 kv = K16[j16];
  float kf[16];
  fp8x16_decode(kv, kf);

  const float4* b4 = (const float4*)&bvec[b * NN + j16 * 16];
  const float* p2 = pc2 + (size_t)b * 3 * NN;
  const float4* p2x = (const float4*)&p2[0 * NN + j16 * 16];
  const float4* p2y = (const float4*)&p2[1 * NN + j16 * 16];
  const float4* p2z = (const float4*)&p2[2 * NN + j16 * 16];

  float S = 0.f, Sx = 0.f, Sy = 0.f, Sz = 0.f;
#pragma unroll
  for (int s = 0; s < 4; ++s) {
    float4 bb = b4[s];
    float4 xx = p2x[s], yy = p2y[s], zz = p2z[s];
    float w0 = kf[s * 4 + 0] * bb.x;
    float w1 = kf[s * 4 + 1] * bb.y;
    float w2 = kf[s * 4 + 2] * bb.z;
    float w3 = kf[s * 4 + 3] * bb.w;
    S += (w0 + w1) + (w2 + w3);
    Sx += w0 * xx.x + w1 * xx.y + w2 * xx.z + w3 * xx.w;
    Sy += w0 * yy.x + w1 * yy.y + w2 * yy.z + w3 * yy.w;
    Sz += w0 * zz.x + w1 * zz.y + w2 * zz.z + w3 * zz.w;
  }
#pragma unroll
  for (int off = 32; off; off >>= 1) {
    S  += __shfl_down(S, off, 64);
    Sx += __shfl_down(Sx, off, 64);
    Sy += __shfl_down(Sy, off, 64);
    Sz += __shfl_down(Sz, off, 64);
  }
  __shared__ float red[4][4];
  int lane = threadIdx.x & 63, wid = threadIdx.x >> 6;
  if (lane == 0) {
    red[wid][0] = S; red[wid][1] = Sx; red[wid][2] = Sy; red[wid][3] = Sz;
  }
  __syncthreads();
  if (threadIdx.x == 0) {
    float kb  = red[0][0] + red[1][0] + red[2][0] + red[3][0];
    float Sxt = red[0][1] + red[1][1] + red[2][1] + red[3][1];
    float Syt = red[0][2] + red[1][2] + red[2][2] + red[3][2];
    float Szt = red[0][3] + red[1][3] + red[2][3] + red[3][3];
    float eps = expf(g_eps[0]) + 0.03f;
    float gam = expf(g_gamma[0]) + 0.03f;
    float power = gam / (gam + eps);
    float av = powf((1.0f / NN) / (kb + 1e-8f), power);
    float denom = av * kb + 1e-6f;
    const float* p1 = pc1 + (size_t)b * 3 * NN;
    size_t o = ((size_t)b * NN + i) * 3;
    out[o + 0] = av * Sxt / denom - p1[0 * NN + i];
    out[o + 1] = av * Syt / denom - p1[1 * NN + i];
    out[o + 2] = av * Szt / denom - p1[2 * NN + i];
  }
}

// ---------------------------------------------------------------------------
extern "C" void kernel_launch(void* const* d_in, const int* in_sizes, int n_in,
                              void* d_out, int out_size, void* d_ws,
                              size_t ws_size, hipStream_t stream) {
  const float* pc1 = (const float*)d_in[0];
  const float* pc2 = (const float*)d_in[1];
  const float* f1 = (const float*)d_in[2];
  const float* f2 = (const float*)d_in[3];
  const float* g_gamma = (const float*)d_in[4];
  const float* g_eps = (const float*)d_in[5];
  float* out = (float*)d_out;

  // Workspace layout
  size_t off = 0;
  char* ws = (char*)d_ws;
  unsigned char* K = (unsigned char*)(ws + off);
  off += (size_t)NB * NN * NN * sizeof(unsigned char);                             // 33.5 MB
  __half* f1t = (__half*)(ws + off); off += (size_t)NB * NN * NC * sizeof(__half); // 4 MB
  __half* f2t = (__half*)(ws + off); off += (size_t)NB * NN * NC * sizeof(__half); // 4 MB
  float* inv1 = (float*)(ws + off); off += (size_t)NB * NN * sizeof(float);
  float* inv2 = (float*)(ws + off); off += (size_t)NB * NN * sizeof(float);
  float* bvec = (float*)(ws + off); off += (size_t)NB * NN * sizeof(float);
  float* part = (float*)(ws + off); off += (size_t)PBLOCKS * NN * sizeof(float);   // 8 MB
  if (ws_size < off) return;  // workspace too small

  norms_kernel<<<dim3(NN / 256, NB, 2), 256, 0, stream>>>(f1, f2, inv1, inv2);
  prep_kernel<<<dim3(NN / 64, NC / 64, NB * 2), 256, 0, stream>>>(
      f1, f2, inv1, inv2, f1t, f2t);
  kmat_mfma_kernel<<<dim3(NN / 128, NN / 128, NB), 256, 0, stream>>>(
      f1t, f2t, pc1, pc2, g_eps, K);

  for (int it = 0; it < MAX_ITER; ++it) {
    fused_pass_kernel<<<dim3(PBLOCKS), 512, 0, stream>>>(
        K, bvec, part, g_gamma, g_eps, it);
    breduce_kernel<<<dim3(NN / 64, NB), 256, 0, stream>>>(
        part, bvec, g_gamma, g_eps);
  }

  kb_flow_kernel<<<dim3(NN, NB), 256, 0, stream>>>(K, bvec, pc1, pc2,
                                                   g_gamma, g_eps, out);
}

// Round 12
// 307.704 us; speedup vs baseline: 1.3087x; 1.0799x over previous
//
#include <hip/hip_runtime.h>
#include <hip/hip_fp16.h>
#include <math.h>

// Problem constants (from setup_inputs): B=2, C=256, N=4096
#define NB 2
#define NC 256
#define NN 4096
#define MAX_ITER 10

#define PBLOCKS 512                    // fused-pass blocks (256 per batch)
#define PCHUNKS 256                    // partial chunks per batch
#define PROWS 16                       // rows per fused-pass block (2 per wave)

#define BK 32                          // K-step (halfs)
#define LDA 40                         // padded LDS row stride in halfs (80 B)
#define C8S 144                        // padded C8 byte stride
#define FROWS 8                        // kb_flow rows per block (R12)

typedef _Float16 half8_t __attribute__((ext_vector_type(8)));
typedef float f32x4 __attribute__((ext_vector_type(4)));
typedef float f32x2 __attribute__((ext_vector_type(2)));

// Decode 16 fp8 (e4m3, packed in uint4) -> 16 floats. HW cvt, gfx950.
__device__ inline void fp8x16_decode(uint4 v, float* o) {
  f32x2 p;
  p = __builtin_amdgcn_cvt_pk_f32_fp8(v.x, false); o[0] = p[0];  o[1] = p[1];
  p = __builtin_amdgcn_cvt_pk_f32_fp8(v.x, true);  o[2] = p[0];  o[3] = p[1];
  p = __builtin_amdgcn_cvt_pk_f32_fp8(v.y, false); o[4] = p[0];  o[5] = p[1];
  p = __builtin_amdgcn_cvt_pk_f32_fp8(v.y, true);  o[6] = p[0];  o[7] = p[1];
  p = __builtin_amdgcn_cvt_pk_f32_fp8(v.z, false); o[8] = p[0];  o[9] = p[1];
  p = __builtin_amdgcn_cvt_pk_f32_fp8(v.z, true);  o[10] = p[0]; o[11] = p[1];
  p = __builtin_amdgcn_cvt_pk_f32_fp8(v.w, false); o[12] = p[0]; o[13] = p[1];
  p = __builtin_amdgcn_cvt_pk_f32_fp8(v.w, true);  o[14] = p[0]; o[15] = p[1];
}

// Decode 8 fp8 (e4m3, packed in uint2) -> 8 floats.
__device__ inline void fp8x8_decode(uint2 v, float* o) {
  f32x2 p;
  p = __builtin_amdgcn_cvt_pk_f32_fp8(v.x, false); o[0] = p[0]; o[1] = p[1];
  p = __builtin_amdgcn_cvt_pk_f32_fp8(v.x, true);  o[2] = p[0]; o[3] = p[1];
  p = __builtin_amdgcn_cvt_pk_f32_fp8(v.y, false); o[4] = p[0]; o[5] = p[1];
  p = __builtin_amdgcn_cvt_pk_f32_fp8(v.y, true);  o[6] = p[0]; o[7] = p[1];
}

// ---------------------------------------------------------------------------
// 1) inv_norm[b,n] = 1/sqrt(sum_c feats[b,c,n]^2 + 1e-6)
__global__ __launch_bounds__(256) void norms_kernel(
    const float* __restrict__ f1, const float* __restrict__ f2,
    float* __restrict__ inv1, float* __restrict__ inv2) {
  int n = blockIdx.x * 256 + threadIdx.x;
  int b = blockIdx.y;
  const float* f = blockIdx.z ? f2 : f1;
  float* o = blockIdx.z ? inv2 : inv1;
  const float* base = f + (size_t)b * NC * NN + n;
  float s = 0.f;
#pragma unroll 8
  for (int c = 0; c < NC; ++c) {
    float v = base[(size_t)c * NN];
    s = fmaf(v, v, s);
  }
  o[b * NN + n] = 1.0f / sqrtf(s + 1e-6f);
}

// ---------------------------------------------------------------------------
// 1b) prep: f_t[b][n][c] = f[b][c][n] * inv[b][n], cast to f16.
__global__ __launch_bounds__(256) void prep_kernel(
    const float* __restrict__ f1, const float* __restrict__ f2,
    const float* __restrict__ inv1, const float* __restrict__ inv2,
    __half* __restrict__ f1t, __half* __restrict__ f2t) {
  int which = blockIdx.z & 1;
  int b = blockIdx.z >> 1;
  const float* f = which ? f2 : f1;
  const float* inv = which ? inv2 : inv1;
  __half* ft = which ? f2t : f1t;
  int n0 = blockIdx.x * 64;
  int c0 = blockIdx.y * 64;

  __shared__ float T[64][65];
  int t = threadIdx.x;
  int lane = t & 63, grp = t >> 6;
#pragma unroll
  for (int p = 0; p < 16; ++p) {
    int c_in = p * 4 + grp;
    T[lane][c_in] = f[((size_t)b * NC + c0 + c_in) * NN + n0 + lane];
  }
  __syncthreads();
#pragma unroll
  for (int p = 0; p < 16; ++p) {
    int n_out = p * 4 + grp;
    float v = T[n_out][lane] * inv[b * NN + n0 + n_out];
    ft[((size_t)b * NN + n0 + n_out) * NC + c0 + lane] = __float2half(v);
  }
}

// ---------------------------------------------------------------------------
// 2) K[b,i,j] = exp((corr-1)/eps') * (dist < 0.25) via f16 MFMA, fp8 store.
// R11's LDS double-buffer (proven: kmat left the top-5, <=47 µs, no spill).
struct __align__(16) SMstage { __half A[2][128 * LDA]; __half B[2][128 * LDA]; };
union SMu { SMstage st; unsigned char C8[128 * C8S]; };

__global__ __launch_bounds__(256) void kmat_mfma_kernel(
    const __half* __restrict__ f1t, const __half* __restrict__ f2t,
    const float* __restrict__ pc1, const float* __restrict__ pc2,
    const float* __restrict__ g_eps, unsigned char* __restrict__ K) {
  int b = blockIdx.z;
  int i0 = blockIdx.y * 128;
  int j0 = blockIdx.x * 128;

  __shared__ SMu sm;
  __shared__ float p1s[4][128];
  __shared__ float p2s[4][128];

  int tid = threadIdx.x;
  if (tid < 128) {
    int i = i0 + tid;
    float x = pc1[((size_t)b * 3 + 0) * NN + i];
    float y = pc1[((size_t)b * 3 + 1) * NN + i];
    float z = pc1[((size_t)b * 3 + 2) * NN + i];
    p1s[0][tid] = x; p1s[1][tid] = y; p1s[2][tid] = z;
    p1s[3][tid] = x * x + y * y + z * z;
  } else {
    int j = j0 + tid - 128;
    float x = pc2[((size_t)b * 3 + 0) * NN + j];
    float y = pc2[((size_t)b * 3 + 1) * NN + j];
    float z = pc2[((size_t)b * 3 + 2) * NN + j];
    p2s[0][tid - 128] = x; p2s[1][tid - 128] = y; p2s[2][tid - 128] = z;
    p2s[3][tid - 128] = x * x + y * y + z * z;
  }
  float inv_eps = 1.0f / (expf(g_eps[0]) + 0.03f);

  const __half* Ag = f1t + ((size_t)b * NN + i0) * NC;
  const __half* Bg = f2t + ((size_t)b * NN + j0) * NC;

  int lane = tid & 63, wid = tid >> 6;
  int m0 = (wid >> 1) * 64, n0 = (wid & 1) * 64;
  int l15 = lane & 15, quad = lane >> 4;

  f32x4 acc[4][4] = {};

  int sr = tid >> 1, sh = tid & 1;
  const __half* Arow = Ag + (size_t)sr * NC + sh * 16;
  const __half* Brow = Bg + (size_t)sr * NC + sh * 16;
  int ldoff = sr * LDA + sh * 16;

  // Prologue: stage step 0 into buf0.
  {
    uint4 a0 = ((const uint4*)Arow)[0], a1 = ((const uint4*)Arow)[1];
    uint4 b0 = ((const uint4*)Brow)[0], b1 = ((const uint4*)Brow)[1];
    uint4* Ad = (uint4*)&sm.st.A[0][ldoff];
    uint4* Bd = (uint4*)&sm.st.B[0][ldoff];
    Ad[0] = a0; Ad[1] = a1;
    Bd[0] = b0; Bd[1] = b1;
  }
  __syncthreads();

  for (int t = 0; t < NC / BK; ++t) {
    int cur = t & 1;
    uint4 a0, a1, b0, b1;
    if (t < NC / BK - 1) {
      const __half* An = Arow + (t + 1) * BK;
      const __half* Bn = Brow + (t + 1) * BK;
      a0 = ((const uint4*)An)[0]; a1 = ((const uint4*)An)[1];
      b0 = ((const uint4*)Bn)[0]; b1 = ((const uint4*)Bn)[1];
    }
    {
      half8_t aF[4], bF[4];
#pragma unroll
      for (int mt = 0; mt < 4; ++mt)
        aF[mt] = *(const half8_t*)&sm.st.A[cur][(m0 + mt * 16 + l15) * LDA + quad * 8];
#pragma unroll
      for (int nt = 0; nt < 4; ++nt)
        bF[nt] = *(const half8_t*)&sm.st.B[cur][(n0 + nt * 16 + l15) * LDA + quad * 8];
#pragma unroll
      for (int mt = 0; mt < 4; ++mt)
#pragma unroll
        for (int nt = 0; nt < 4; ++nt)
          acc[mt][nt] = __builtin_amdgcn_mfma_f32_16x16x32_f16(
              aF[mt], bF[nt], acc[mt][nt], 0, 0, 0);
    }
    if (t < NC / BK - 1) {
      uint4* Ad = (uint4*)&sm.st.A[cur ^ 1][ldoff];
      uint4* Bd = (uint4*)&sm.st.B[cur ^ 1][ldoff];
      Ad[0] = a0; Ad[1] = a1;
      Bd[0] = b0; Bd[1] = b1;
    }
    __syncthreads();
  }

  float c2x[4], c2y[4], c2z[4], c2n[4];
#pragma unroll
  for (int nt = 0; nt < 4; ++nt) {
    int c = n0 + nt * 16 + l15;
    c2x[nt] = p2s[0][c]; c2y[nt] = p2s[1][c];
    c2z[nt] = p2s[2][c]; c2n[nt] = p2s[3][c];
  }
#pragma unroll
  for (int mt = 0; mt < 4; ++mt) {
#pragma unroll
    for (int rr = 0; rr < 4; ++rr) {
      int row = m0 + mt * 16 + quad * 4 + rr;
      float px = p1s[0][row], py = p1s[1][row], pz = p1s[2][row];
      float n1 = p1s[3][row];
#pragma unroll
      for (int nt = 0; nt < 4; ++nt) {
        float corr = acc[mt][nt][rr];
        float dist = n1 + c2n[nt] - 2.0f * (px * c2x[nt] + py * c2y[nt] + pz * c2z[nt]);
        float kv = (dist < 0.25f) ? __expf((corr - 1.0f) * inv_eps) : 0.0f;
        unsigned int pk = (unsigned int)__builtin_amdgcn_cvt_pk_fp8_f32(kv, kv, 0, false);
        sm.C8[row * C8S + n0 + nt * 16 + l15] = (unsigned char)(pk & 0xFF);
      }
    }
  }
  __syncthreads();

  // Coalesced fp8 store: 8 threads cover a 128B row, 32 rows per sweep.
  int c8 = tid & 7, rg = tid >> 3;
#pragma unroll
  for (int s = 0; s < 4; ++s) {
    int row = s * 32 + rg;
    uint4 v = *(uint4*)&sm.C8[row * C8S + c8 * 16];
    *(uint4*)&K[((size_t)b * NN + i0 + row) * NN + j0 + c8 * 16] = v;
  }
}

// ---------------------------------------------------------------------------
// 3) Fused Sinkhorn pass over fp8 K. R7/R11's 512-thread two-phase version.
__global__ __launch_bounds__(512) void fused_pass_kernel(
    const unsigned char* __restrict__ K, const float* __restrict__ bvec,
    float* __restrict__ part, const float* __restrict__ g_gamma,
    const float* __restrict__ g_eps, int pass) {
  __shared__ float wgt_s[PROWS];  // 64 B

  int g = blockIdx.x;            // 0..511
  int batch = g >> 8;
  int row0 = (g & 255) * PROWS;
  int tid = threadIdx.x;
  int w = tid >> 6, l = tid & 63;  // w: 0..7
  const unsigned char* Kb = K + (size_t)batch * NN * NN;

  float eps = expf(g_eps[0]) + 0.03f;
  float gam = expf(g_gamma[0]) + 0.03f;
  float power = gam / (gam + eps);
  const float probN = 1.0f / NN;

  if (pass > 0) {
    int rbase = row0 + w * 2;  // 2 rows per wave

    uint4 kraw[2][4];
#pragma unroll
    for (int r = 0; r < 2; ++r) {
      const uint4* Kr = (const uint4*)(Kb + (size_t)(rbase + r) * NN);
#pragma unroll
      for (int q = 0; q < 4; ++q) kraw[r][q] = Kr[q * 64 + l];
    }

    float d0[2] = {}, d1[2] = {}, d2[2] = {}, d3[2] = {};
#pragma unroll
    for (int q = 0; q < 4; ++q) {
      float bq[16];
      const float4* bp = (const float4*)&bvec[batch * NN + (q * 64 + l) * 16];
#pragma unroll
      for (int s = 0; s < 4; ++s) {
        float4 bb = bp[s];
        bq[s * 4 + 0] = bb.x; bq[s * 4 + 1] = bb.y;
        bq[s * 4 + 2] = bb.z; bq[s * 4 + 3] = bb.w;
      }
#pragma unroll
      for (int r = 0; r < 2; ++r) {
        float kf[16];
        fp8x16_decode(kraw[r][q], kf);
#pragma unroll
        for (int s = 0; s < 4; ++s) {
          d0[r] = fmaf(kf[s * 4 + 0], bq[s * 4 + 0], d0[r]);
          d1[r] = fmaf(kf[s * 4 + 1], bq[s * 4 + 1], d1[r]);
          d2[r] = fmaf(kf[s * 4 + 2], bq[s * 4 + 2], d2[r]);
          d3[r] = fmaf(kf[s * 4 + 3], bq[s * 4 + 3], d3[r]);
        }
      }
    }
#pragma unroll
    for (int r = 0; r < 2; ++r) {
      float kbs = (d0[r] + d1[r]) + (d2[r] + d3[r]);
#pragma unroll
      for (int off = 1; off < 64; off <<= 1) kbs += __shfl_xor(kbs, off, 64);
      if (l == 0) wgt_s[w * 2 + r] = __powf(probN / (kbs + 1e-8f), power);
    }
  }

  __builtin_amdgcn_sched_barrier(0);

  uint2 k2[PROWS];
#pragma unroll
  for (int r = 0; r < PROWS; ++r)
    k2[r] = *(const uint2*)(Kb + (size_t)(row0 + r) * NN + w * 512 + l * 8);

  if (pass > 0) __syncthreads();  // wgt_s ready (load latency hides here)

  float ps[8];
#pragma unroll
  for (int e = 0; e < 8; ++e) ps[e] = 0.f;
#pragma unroll
  for (int r = 0; r < PROWS; ++r) {
    float wr = (pass == 0) ? probN : wgt_s[r];
    float kf[8];
    fp8x8_decode(k2[r], kf);
#pragma unroll
    for (int e = 0; e < 8; ++e) ps[e] = fmaf(kf[e], wr, ps[e]);
  }

  float* pout = &part[(size_t)g * NN + w * 512 + l * 8];
  *(float4*)&pout[0] = make_float4(ps[0], ps[1], ps[2], ps[3]);
  *(float4*)&pout[4] = make_float4(ps[4], ps[5], ps[6], ps[7]);
}

// ---------------------------------------------------------------------------
// 3b) b[j] = (probN / (sum_k part[b,k,j] + 1e-8))^power
__global__ __launch_bounds__(256) void breduce_kernel(
    const float* __restrict__ part, float* __restrict__ bvec,
    const float* __restrict__ g_gamma, const float* __restrict__ g_eps) {
  int b = blockIdx.y;
  int c0 = blockIdx.x * 64;
  int t = threadIdx.x;
  int cl = t & 63, kg = t >> 6;
  const float* p = part + (size_t)(b * PCHUNKS + kg * 64) * NN + c0 + cl;
  float s = 0.f;
#pragma unroll 8
  for (int k = 0; k < 64; ++k) s += p[(size_t)k * NN];
  __shared__ float red[4][64];
  red[kg][cl] = s;
  __syncthreads();
  if (t < 64) {
    float tot = (red[0][t] + red[1][t]) + (red[2][t] + red[3][t]);
    float eps = expf(g_eps[0]) + 0.03f;
    float gam = expf(g_gamma[0]) + 0.03f;
    float power = gam / (gam + eps);
    bvec[b * NN + c0 + t] = __powf((1.0f / NN) / (tot + 1e-8f), power);
  }
}

// ---------------------------------------------------------------------------
// 4) Final pass fused: Kb + Sxyz, then a_10 and flow. fp8 K.
// R12: FROWS=8 rows per block (was 1). Counters showed kb_flow at 47.7 µs,
// HBM 388 GB/s, VALUBusy 23% — per-block overhead + 557 MB of L2 re-reads
// of bvec/p2 (identical across all 4096 blocks/batch). Now b and p2 are
// loaded into registers ONCE and amortized over 8 rows; K rows preloaded
// in groups of 4 (4 outstanding 16B loads); per-row shfl reduce unchanged;
// threads 0..7 finalize all 8 rows after one sync. Per-thread compute and
// reduction expressions identical to R11's version.
__global__ __launch_bounds__(256) void kb_flow_kernel(
    const unsigned char* __restrict__ K, const float* __restrict__ bvec,
    const float* __restrict__ pc1, const float* __restrict__ pc2,
    const float* __restrict__ g_gamma, const float* __restrict__ g_eps,
    float* __restrict__ out) {
  int b = blockIdx.y;
  int i0 = blockIdx.x * FROWS;
  int tid = threadIdx.x;           // covers cols tid*16 .. +15
  int lane = tid & 63, wid = tid >> 6;

  // Load b and p2 ONCE (amortized over FROWS rows).
  const float4* b4 = (const float4*)&bvec[b * NN + tid * 16];
  const float* p2 = pc2 + (size_t)b * 3 * NN;
  const float4* p2x = (const float4*)&p2[0 * NN + tid * 16];
  const float4* p2y = (const float4*)&p2[1 * NN + tid * 16];
  const float4* p2z = (const float4*)&p2[2 * NN + tid * 16];
  float4 bb[4], xx[4], yy[4], zz[4];
#pragma unroll
  for (int s = 0; s < 4; ++s) {
    bb[s] = b4[s];
    xx[s] = p2x[s]; yy[s] = p2y[s]; zz[s] = p2z[s];
  }

  __shared__ float red[4][FROWS][4];  // [wave][row][comp] = 512 B

  const unsigned char* Kb = K + (size_t)b * NN * NN;
#pragma unroll
  for (int rg = 0; rg < FROWS / 4; ++rg) {
    // Preload 4 rows' K slices (4 outstanding 16B loads).
    uint4 kv[4];
#pragma unroll
    for (int r = 0; r < 4; ++r)
      kv[r] = *(const uint4*)(Kb + (size_t)(i0 + rg * 4 + r) * NN + tid * 16);
#pragma unroll
    for (int r = 0; r < 4; ++r) {
      float kf[16];
      fp8x16_decode(kv[r], kf);
      float S = 0.f, Sx = 0.f, Sy = 0.f, Sz = 0.f;
#pragma unroll
      for (int s = 0; s < 4; ++s) {
        float w0 = kf[s * 4 + 0] * bb[s].x;
        float w1 = kf[s * 4 + 1] * bb[s].y;
        float w2 = kf[s * 4 + 2] * bb[s].z;
        float w3 = kf[s * 4 + 3] * bb[s].w;
        S += (w0 + w1) + (w2 + w3);
        Sx += w0 * xx[s].x + w1 * xx[s].y + w2 * xx[s].z + w3 * xx[s].w;
        Sy += w0 * yy[s].x + w1 * yy[s].y + w2 * yy[s].z + w3 * yy[s].w;
        Sz += w0 * zz[s].x + w1 * zz[s].y + w2 * zz[s].z + w3 * zz[s].w;
      }
#pragma unroll
      for (int off = 32; off; off >>= 1) {
        S  += __shfl_down(S, off, 64);
        Sx += __shfl_down(Sx, off, 64);
        Sy += __shfl_down(Sy, off, 64);
        Sz += __shfl_down(Sz, off, 64);
      }
      if (lane == 0) {
        red[wid][rg * 4 + r][0] = S;
        red[wid][rg * 4 + r][1] = Sx;
        red[wid][rg * 4 + r][2] = Sy;
        red[wid][rg * 4 + r][3] = Sz;
      }
    }
  }
  __syncthreads();
  if (tid < FROWS) {
    int i = i0 + tid;
    float kb  = red[0][tid][0] + red[1][tid][0] + red[2][tid][0] + red[3][tid][0];
    float Sxt = red[0][tid][1] + red[1][tid][1] + red[2][tid][1] + red[3][tid][1];
    float Syt = red[0][tid][2] + red[1][tid][2] + red[2][tid][2] + red[3][tid][2];
    float Szt = red[0][tid][3] + red[1][tid][3] + red[2][tid][3] + red[3][tid][3];
    float eps = expf(g_eps[0]) + 0.03f;
    float gam = expf(g_gamma[0]) + 0.03f;
    float power = gam / (gam + eps);
    float av = powf((1.0f / NN) / (kb + 1e-8f), power);
    float denom = av * kb + 1e-6f;
    const float* p1 = pc1 + (size_t)b * 3 * NN;
    size_t o = ((size_t)b * NN + i) * 3;
    out[o + 0] = av * Sxt / denom - p1[0 * NN + i];
    out[o + 1] = av * Syt / denom - p1[1 * NN + i];
    out[o + 2] = av * Szt / denom - p1[2 * NN + i];
  }
}

// ---------------------------------------------------------------------------
extern "C" void kernel_launch(void* const* d_in, const int* in_sizes, int n_in,
                              void* d_out, int out_size, void* d_ws,
                              size_t ws_size, hipStream_t stream) {
  const float* pc1 = (const float*)d_in[0];
  const float* pc2 = (const float*)d_in[1];
  const float* f1 = (const float*)d_in[2];
  const float* f2 = (const float*)d_in[3];
  const float* g_gamma = (const float*)d_in[4];
  const float* g_eps = (const float*)d_in[5];
  float* out = (float*)d_out;

  // Workspace layout
  size_t off = 0;
  char* ws = (char*)d_ws;
  unsigned char* K = (unsigned char*)(ws + off);
  off += (size_t)NB * NN * NN * sizeof(unsigned char);                             // 33.5 MB
  __half* f1t = (__half*)(ws + off); off += (size_t)NB * NN * NC * sizeof(__half); // 4 MB
  __half* f2t = (__half*)(ws + off); off += (size_t)NB * NN * NC * sizeof(__half); // 4 MB
  float* inv1 = (float*)(ws + off); off += (size_t)NB * NN * sizeof(float);
  float* inv2 = (float*)(ws + off); off += (size_t)NB * NN * sizeof(float);
  float* bvec = (float*)(ws + off); off += (size_t)NB * NN * sizeof(float);
  float* part = (float*)(ws + off); off += (size_t)PBLOCKS * NN * sizeof(float);   // 8 MB
  if (ws_size < off) return;  // workspace too small

  norms_kernel<<<dim3(NN / 256, NB, 2), 256, 0, stream>>>(f1, f2, inv1, inv2);
  prep_kernel<<<dim3(NN / 64, NC / 64, NB * 2), 256, 0, stream>>>(
      f1, f2, inv1, inv2, f1t, f2t);
  kmat_mfma_kernel<<<dim3(NN / 128, NN / 128, NB), 256, 0, stream>>>(
      f1t, f2t, pc1, pc2, g_eps, K);

  for (int it = 0; it < MAX_ITER; ++it) {
    fused_pass_kernel<<<dim3(PBLOCKS), 512, 0, stream>>>(
        K, bvec, part, g_gamma, g_eps, it);
    breduce_kernel<<<dim3(NN / 64, NB), 256, 0, stream>>>(
        part, bvec, g_gamma, g_eps);
  }

  kb_flow_kernel<<<dim3(NN / FROWS, NB), 256, 0, stream>>>(
      K, bvec, pc1, pc2, g_gamma, g_eps, out);
}